// Round 2
// baseline (317.579 us; speedup 1.0000x reference)
//
#include <hip/hip_runtime.h>
#include <math.h>

// Problem constants (from reference setup_inputs)
#define NC 80            // NUM_CLASSES
constexpr int BS  = 16;      // batch
constexpr int NA  = 33600;   // anchors
constexpr int NG  = 64;      // gt boxes
constexpr int TPB = 256;
constexpr int NBLK = (NA + TPB - 1) / TPB;  // 132 blocks per batch
constexpr int NW   = TPB / 64;              // 4 waves per block

// branchless insert of v into descending top-3 (t0 >= t1 >= t2): 6 VALU ops
__device__ __forceinline__ void ins3(float v, float& t0, float& t1, float& t2) {
  t2 = fmaxf(t2, fminf(v, t1));   // uses old t1
  t1 = fmaxf(t1, fminf(v, t0));   // uses old t0
  t0 = fmaxf(t0, v);
}

// 64-lane butterfly top3 merge
__device__ __forceinline__ void wave_top3(float& t0, float& t1, float& t2) {
  #pragma unroll
  for (int off = 32; off > 0; off >>= 1) {
    float u0 = __shfl_xor(t0, off, 64);
    float u1 = __shfl_xor(t1, off, 64);
    float u2 = __shfl_xor(t2, off, 64);
    ins3(u0, t0, t1, t2);
    ins3(u1, t0, t1, t2);
    ins3(u2, t0, t1, t2);
  }
}

// ---------------------------------------------------------------------------
// F: dedicated streaming zero-fill of the whole score tensor (172 MB).
// Pure grid-strided float4 stores — same shape as the rocclr fill kernel
// that sustains ~6.36 TB/s. Runs BEFORE p1 (stream order), so p1's one-hot
// scatter needs no intra-kernel fence at all.
// ---------------------------------------------------------------------------
__global__ __launch_bounds__(TPB) void fill_kernel(float4* __restrict__ s4, long n4)
{
  const long stride = (long)gridDim.x * TPB;
  const float4 z = make_float4(0.f, 0.f, 0.f, 0.f);
  for (long i = (long)blockIdx.x * TPB + threadIdx.x; i < n4; i += stride)
    s4[i] = z;
}

// ---------------------------------------------------------------------------
// P1: slim main pass (no score fill, no barrier #2). Stage GT in LDS ->
// barrier -> IoU loop (exact IEEE divide: every comparison bit-identical to
// numpy) -> per-anchor outputs + direct one-hot scatter (fenced by the fill
// KERNEL completing first) -> per-wave max reduce -> per-wave max store.
// Top-3 tracking (only consumed by the never-in-practice fallback) is
// deferred behind a wave-uniform wmax<=0.3 gate: if the global batch max
// ends up <=0.3 then EVERY wave took the rare path and wrote its triple, so
// the slow consumer always sees valid data. The per-wave max is stored in
// blockTop[...][0] (t0 == wmax on the slow path) — workspace footprint is
// exactly the previously-verified BS*NBLK*NW*3 floats (~101 KB), no growth.
// Invalid GT boxes are zeroed in LDS so their IoU is exactly 0.0.
// ---------------------------------------------------------------------------
__global__ __launch_bounds__(TPB) void p1_kernel(
    const float4* __restrict__ pd, const float4* __restrict__ gt,
    const int* __restrict__ glab, const int* __restrict__ gmask,
    float* __restrict__ outL, float4* __restrict__ outB,
    float* __restrict__ outS, float* __restrict__ outF,
    float* __restrict__ outI, float* __restrict__ blockTop)
{
  #pragma clang fp contract(off)
  const int b   = blockIdx.y;
  const int tid = threadIdx.x;

  __shared__ float4 sbox[NG];
  __shared__ float  sarea[NG];
  __shared__ int    slab[NG];
  __shared__ int    svalid[NG];

  const int a0  = blockIdx.x * TPB;
  const int a   = a0 + tid;
  const bool inb = a < NA;

  // ---- own pd box (issued before the barrier) ----
  float4 p = make_float4(0.f, 0.f, 0.f, 0.f);
  if (inb) p = pd[(long)b * NA + a];

  // ---- stage gt into LDS ----
  if (tid < NG) {
    int v = gmask[b * NG + tid];
    float4 g = gt[b * NG + tid];
    if (!v) g = make_float4(0.f, 0.f, 0.f, 0.f);  // zero-box => iou == 0
    sbox[tid]   = g;
    sarea[tid]  = (g.z - g.x) * (g.w - g.y);
    slab[tid]   = glab[b * NG + tid];
    svalid[tid] = v;
  }
  __syncthreads();

  float best = -1.f;
  int   bidx = 0;
  float a2 = 0.f;

  if (inb) {
    a2 = (p.z - p.x) * (p.w - p.y);
    #pragma unroll 8
    for (int g = 0; g < NG; ++g) {
      float4 gb = sbox[g];
      float iw = fminf(gb.z, p.z) - fmaxf(gb.x, p.x);
      float ih = fminf(gb.w, p.w) - fmaxf(gb.y, p.y);
      iw = fmaxf(iw, 0.f);
      ih = fmaxf(ih, 0.f);
      float inter = iw * ih;
      float den   = sarea[g] + a2 - inter + 1e-9f;
      float iou   = inter / den;                 // exact IEEE, matches np
      bidx = (iou > best) ? g : bidx;            // first-index tie-break
      best = fmaxf(best, iou);
    }
    bool fg    = best > 0.3f;
    bool maskv = fg && (svalid[bidx] != 0);
    int  blab  = slab[bidx];
    long ga = (long)b * NA + a;
    outL[ga] = maskv ? (float)blab : 80.f;       // BG_IDX = 80
    float m = maskv ? 1.f : 0.f;
    float4 gb = sbox[bidx];
    outB[ga] = make_float4(gb.x * m, gb.y * m, gb.z * m, gb.w * m);
    outF[ga] = fg ? 1.f : 0.f;
    outI[ga] = (float)bidx;
    if (maskv) outS[ga * NC + blab] = 1.f;       // rows pre-zeroed by fill_kernel
  }

  // ---- per-wave max of best (cheap: 6 shfl + 6 fmax) ----
  float wmax = best;
  #pragma unroll
  for (int off = 32; off > 0; off >>= 1)
    wmax = fmaxf(wmax, __shfl_xor(wmax, off, 64));

  float* bt = blockTop + (((long)b * NBLK + blockIdx.x) * NW + (tid >> 6)) * 3;

  // ---- rare path: this wave cannot prove fg. Recompute ious with full
  // top-3 tracking and publish the wave triple's tail (t1,t2). Global
  // need_fb implies ALL waves land here, so the triples the slow consumer
  // reads are always freshly written. (OOB tail waves publish -inf tails
  // and wmax=-1 — both below any real iou >= 0, so the batch top-3, which
  // is always >= 0 with 33600 real anchors, is unaffected.) ----
  if (wmax <= 0.3f) {                            // wave-uniform branch
    float t0 = -INFINITY, t1 = -INFINITY, t2 = -INFINITY;
    if (inb) {
      #pragma unroll 4
      for (int g = 0; g < NG; ++g) {
        float4 gb = sbox[g];
        float iw = fminf(gb.z, p.z) - fmaxf(gb.x, p.x);
        float ih = fminf(gb.w, p.w) - fmaxf(gb.y, p.y);
        iw = fmaxf(iw, 0.f);
        ih = fmaxf(ih, 0.f);
        float inter = iw * ih;
        float den   = sarea[g] + a2 - inter + 1e-9f;
        float iou   = inter / den;
        ins3(iou, t0, t1, t2);
      }
    }
    wave_top3(t0, t1, t2);
    if ((tid & 63) == 0) { bt[1] = t1; bt[2] = t2; }
  }
  // ---- unconditional per-wave max (slot 0; t0 == wmax on the slow path) ----
  if ((tid & 63) == 0) bt[0] = wmax;
}

// ---------------------------------------------------------------------------
// P3: fallback fixup. Fast path: reduce max over the per-wave maxima in
// blockTop[...][0] (528 stride-3 floats/batch, L2-hot) and exit uniformly
// if the batch has any fg anchor — before any ballot / GT staging / triple
// work. Slow path (never taken on this data, kept correct): ballot over
// gmask, full top-3 reduce of blockTop triples for min_iou, per-anchor
// rewrite + one-hot scatter. need_fb implies P1 wrote the batch entirely as
// background (scores all zero), so only rewrites are needed; target_gt_idx
// is fallback-independent -> not rewritten.
// ---------------------------------------------------------------------------
__global__ __launch_bounds__(TPB) void p3_kernel(
    const float4* __restrict__ pd, const float4* __restrict__ gt,
    const int* __restrict__ glab, const int* __restrict__ gmask,
    const float* __restrict__ blockTop,
    float* __restrict__ outL, float4* __restrict__ outB,
    float* __restrict__ outS, float* __restrict__ outF)
{
  #pragma clang fp contract(off)
  const int b   = blockIdx.y;
  const int tid = threadIdx.x;

  __shared__ float  swm[NW];
  __shared__ float  sM;
  __shared__ float  swt[NW][3];
  __shared__ float  sres;
  __shared__ int    sfb;
  __shared__ float4 sbox[NG];
  __shared__ float  sarea[NG];
  __shared__ int    slab[NG];
  __shared__ int    svalid[NG];

  // ---- fast decision: max over this batch's per-wave maxima (slot 0) ----
  float m = -INFINITY;
  for (int i = tid; i < NBLK * NW; i += TPB)
    m = fmaxf(m, blockTop[((long)b * NBLK * NW + i) * 3]);
  #pragma unroll
  for (int off = 32; off > 0; off >>= 1)
    m = fmaxf(m, __shfl_xor(m, off, 64));
  const int lane = tid & 63, wid = tid >> 6;
  if (lane == 0) swm[wid] = m;
  __syncthreads();
  if (tid == 0) {
    float r = swm[0];
    #pragma unroll
    for (int w = 1; w < NW; ++w) r = fmaxf(r, swm[w]);
    sM = r;
  }
  __syncthreads();
  if (sM > 0.3f) return;       // common case: batch has fg -> uniform exit

  // ================= slow path (cold, correctness only) =================
  int gv = (tid < NG) ? gmask[b * NG + tid] : 0;
  unsigned long long bal = __ballot(gv != 0);  // valid in wave 0

  // reduce batch's per-wave top3 triples
  float t0 = -INFINITY, t1 = -INFINITY, t2 = -INFINITY;
  for (int i = tid; i < NBLK * NW; i += TPB) {
    const float* bt = blockTop + ((long)b * NBLK * NW + i) * 3;
    ins3(bt[0], t0, t1, t2);
    ins3(bt[1], t0, t1, t2);
    ins3(bt[2], t0, t1, t2);
  }
  wave_top3(t0, t1, t2);
  if (lane == 0) { swt[wid][0] = t0; swt[wid][1] = t1; swt[wid][2] = t2; }
  __syncthreads();
  if (tid == 0) {
    float r0 = swt[0][0], r1 = swt[0][1], r2 = swt[0][2];
    #pragma unroll
    for (int w = 1; w < NW; ++w) {
      ins3(swt[w][0], r0, r1, r2);
      ins3(swt[w][1], r0, r1, r2);
      ins3(swt[w][2], r0, r1, r2);
    }
    sfb  = (!(r0 > 0.3f) && bal != 0ULL) ? 1 : 0;
    sres = r2;
  }
  // stage gt into LDS (overlaps the decision barrier)
  if (tid < NG) {
    float4 g = gt[b * NG + tid];
    if (!gv) g = make_float4(0.f, 0.f, 0.f, 0.f);
    sbox[tid]   = g;
    sarea[tid]  = (g.z - g.x) * (g.w - g.y);
    slab[tid]   = glab[b * NG + tid];
    svalid[tid] = gv;
  }
  __syncthreads();
  if (sfb == 0) return;        // uniform exit (no barriers after this)
  const float minio = sres;

  const int a = blockIdx.x * TPB + tid;
  if (a >= NA) return;

  float4 p  = pd[(long)b * NA + a];
  float  a2 = (p.z - p.x) * (p.w - p.y);
  float best = -1.f;
  int   bidx = 0;
  #pragma unroll 8
  for (int g = 0; g < NG; ++g) {
    float4 gb = sbox[g];
    float iw = fminf(gb.z, p.z) - fmaxf(gb.x, p.x);
    float ih = fminf(gb.w, p.w) - fmaxf(gb.y, p.y);
    iw = fmaxf(iw, 0.f);
    ih = fmaxf(ih, 0.f);
    float inter = iw * ih;
    float den   = sarea[g] + a2 - inter + 1e-9f;
    float iou   = inter / den;
    bidx = (iou > best) ? g : bidx;
    best = fmaxf(best, iou);
  }
  // fallback fg: max over valid of overlaps >= min_iou. With zero-boxes and
  // has_valid guaranteed here, max over all g == max over valid g.
  bool fg    = best >= minio;
  bool maskv = fg && (svalid[bidx] != 0);
  int  blab  = slab[bidx];
  long ga = (long)b * NA + a;
  outL[ga] = maskv ? (float)blab : 80.f;
  float mm = maskv ? 1.f : 0.f;
  float4 gb = sbox[bidx];
  outB[ga] = make_float4(gb.x * mm, gb.y * mm, gb.z * mm, gb.w * mm);
  outF[ga] = fg ? 1.f : 0.f;
  if (maskv) outS[ga * NC + blab] = 1.f;  // scores were all-zero for this batch
}

// ---------------------------------------------------------------------------
// launch
// ---------------------------------------------------------------------------
extern "C" void kernel_launch(void* const* d_in, const int* in_sizes, int n_in,
                              void* d_out, int out_size, void* d_ws, size_t ws_size,
                              hipStream_t stream) {
  // inputs (setup_inputs order): 0 pd_scores (unused), 1 pd_bboxes,
  // 2 anc_points (unused), 3 gt_labels, 4 gt_bboxes, 5 mask_gt
  const float4* pd    = (const float4*)d_in[1];
  const int*    glab  = (const int*)d_in[3];
  const float4* gt    = (const float4*)d_in[4];
  const int*    gmask = (const int*)d_in[5];

  float* outf = (float*)d_out;
  // outputs concatenated flat in return order (all as float32):
  // target_labels [16,33600], target_bboxes [16,33600,4],
  // target_scores [16,33600,80], fg_mask [16,33600], target_gt_idx [16,33600]
  float*  outL = outf;
  float4* outB = (float4*)(outf + (long)BS * NA);
  float*  outS = outf + (long)BS * NA * 5;
  float*  outF = outf + (long)BS * NA * 5 + (long)BS * NA * NC;
  float*  outI = outF + (long)BS * NA;

  // workspace: per-wave {max, top3-tail} triples — exactly the proven
  // BS*NBLK*NW*3 floats (~101 KB), no growth vs the verified baseline.
  float* blockTop = (float*)d_ws;

  // 1) stream-fill the 172 MB score tensor at full write BW (~6.3 TB/s)
  const long n4 = (long)BS * NA * NC / 4;
  fill_kernel<<<2048, TPB, 0, stream>>>((float4*)outS, n4);

  // 2) slim compute pass (exact-IEEE IoU; scatter ordered after the fill)
  dim3 grid(NBLK, BS);
  p1_kernel<<<grid, TPB, 0, stream>>>(pd, gt, glab, gmask,
                                      outL, outB, outS, outF, outI, blockTop);

  // 3) fallback check (fast-exit on per-wave maxima) / rare fixup
  p3_kernel<<<grid, TPB, 0, stream>>>(pd, gt, glab, gmask, blockTop,
                                      outL, outB, outS, outF);
}

// Round 3
// 295.306 us; speedup vs baseline: 1.0754x; 1.0754x over previous
//
#include <hip/hip_runtime.h>
#include <math.h>

// Problem constants (from reference setup_inputs)
#define NC 80            // NUM_CLASSES
constexpr int BS  = 16;      // batch
constexpr int NA  = 33600;   // anchors
constexpr int NG  = 64;      // gt boxes
constexpr int TPB = 256;
constexpr int NBLK = (NA + TPB - 1) / TPB;  // 132 blocks per batch
constexpr int NW   = TPB / 64;              // 4 waves per block

// branchless insert of v into descending top-3 (t0 >= t1 >= t2): 6 VALU ops
__device__ __forceinline__ void ins3(float v, float& t0, float& t1, float& t2) {
  t2 = fmaxf(t2, fminf(v, t1));   // uses old t1
  t1 = fmaxf(t1, fminf(v, t0));   // uses old t0
  t0 = fmaxf(t0, v);
}

// 64-lane butterfly top3 merge
__device__ __forceinline__ void wave_top3(float& t0, float& t1, float& t2) {
  #pragma unroll
  for (int off = 32; off > 0; off >>= 1) {
    float u0 = __shfl_xor(t0, off, 64);
    float u1 = __shfl_xor(t1, off, 64);
    float u2 = __shfl_xor(t2, off, 64);
    ins3(u0, t0, t1, t2);
    ins3(u1, t0, t1, t2);
    ins3(u2, t0, t1, t2);
  }
}

// ---------------------------------------------------------------------------
// P1: fused main pass (the structure that measured 297.9 µs; R2 proved the
// split-fill variant is −19 µs worse). Order: stage LDS -> barrier -> issue
// zero-fill stores (drain overlaps the IoU loop; only barrier #2 waits on
// them) -> IoU loop (exact IEEE divide: every comparison bit-identical to
// numpy) -> per-anchor outputs -> per-wave max reduce -> DEFERRED top-3
// (only under the wave-uniform wmax<=0.3 gate: global fallback implies ALL
// waves took this path, so the slow consumer always sees fresh triples) ->
// barrier #2 (fences fill vs scatter) -> one-hot scatter. blockTop slot 0
// carries wmax (== t0 on the slow path); footprint is exactly the proven
// BS*NBLK*NW*3 floats. Invalid GT boxes are zeroed in LDS so iou == 0.0.
// ---------------------------------------------------------------------------
__global__ __launch_bounds__(TPB) void p1_kernel(
    const float4* __restrict__ pd, const float4* __restrict__ gt,
    const int* __restrict__ glab, const int* __restrict__ gmask,
    float* __restrict__ outL, float4* __restrict__ outB,
    float* __restrict__ outS, float* __restrict__ outF,
    float* __restrict__ outI, float* __restrict__ blockTop)
{
  #pragma clang fp contract(off)
  const int b   = blockIdx.y;
  const int tid = threadIdx.x;

  __shared__ float4 sbox[NG];
  __shared__ float  sarea[NG];
  __shared__ int    slab[NG];
  __shared__ int    svalid[NG];

  const int a0  = blockIdx.x * TPB;
  const int a   = a0 + tid;
  const bool inb = a < NA;

  // ---- own pd box (issued before the barrier) ----
  float4 p = make_float4(0.f, 0.f, 0.f, 0.f);
  if (inb) p = pd[(long)b * NA + a];

  // ---- stage gt into LDS ----
  if (tid < NG) {
    int v = gmask[b * NG + tid];
    float4 g = gt[b * NG + tid];
    if (!v) g = make_float4(0.f, 0.f, 0.f, 0.f);  // zero-box => iou == 0
    sbox[tid]   = g;
    sarea[tid]  = (g.z - g.x) * (g.w - g.y);
    slab[tid]   = glab[b * NG + tid];
    svalid[tid] = v;
  }
  __syncthreads();

  // ---- streaming zero-fill of this block's score rows: issued AFTER the
  // barrier so the stores drain while the IoU loop runs (only barrier #2
  // waits on vmcnt(0)) ----
  const int nA = min(TPB, NA - a0);
  float4* s4 = (float4*)(outS + ((long)b * NA + a0) * NC);
  const int cnt4 = nA * (NC / 4);
  for (int i = tid; i < cnt4; i += TPB) s4[i] = make_float4(0.f, 0.f, 0.f, 0.f);

  float best = -1.f;
  int   bidx = 0;
  float a2 = 0.f;
  bool  maskv = false;
  int   blab  = 0;

  if (inb) {
    a2 = (p.z - p.x) * (p.w - p.y);
    #pragma unroll 8
    for (int g = 0; g < NG; ++g) {
      float4 gb = sbox[g];
      float iw = fminf(gb.z, p.z) - fmaxf(gb.x, p.x);
      float ih = fminf(gb.w, p.w) - fmaxf(gb.y, p.y);
      iw = fmaxf(iw, 0.f);
      ih = fmaxf(ih, 0.f);
      float inter = iw * ih;
      float den   = sarea[g] + a2 - inter + 1e-9f;
      float iou   = inter / den;                 // exact IEEE, matches np
      bidx = (iou > best) ? g : bidx;            // first-index tie-break
      best = fmaxf(best, iou);
    }
    bool fg = best > 0.3f;
    maskv = fg && (svalid[bidx] != 0);
    blab  = slab[bidx];
    long ga = (long)b * NA + a;
    outL[ga] = maskv ? (float)blab : 80.f;       // BG_IDX = 80
    float m = maskv ? 1.f : 0.f;
    float4 gb = sbox[bidx];
    outB[ga] = make_float4(gb.x * m, gb.y * m, gb.z * m, gb.w * m);
    outF[ga] = fg ? 1.f : 0.f;
    outI[ga] = (float)bidx;
  }

  // ---- per-wave max of best (cheap: 6 shfl + 6 fmax) ----
  float wmax = best;
  #pragma unroll
  for (int off = 32; off > 0; off >>= 1)
    wmax = fmaxf(wmax, __shfl_xor(wmax, off, 64));

  float* bt = blockTop + (((long)b * NBLK + blockIdx.x) * NW + (tid >> 6)) * 3;

  // ---- rare path: this wave cannot prove fg. Recompute ious with full
  // top-3 tracking and publish the triple's tail. Global need_fb implies
  // ALL waves land here, so the triples the slow consumer reads are always
  // freshly written. (OOB tail waves publish -inf tails and wmax=-1 — both
  // below any real iou >= 0, so the batch top-3, always >= 0 with 33600
  // real anchors, is unaffected.) ----
  if (wmax <= 0.3f) {                            // wave-uniform branch
    float t0 = -INFINITY, t1 = -INFINITY, t2 = -INFINITY;
    if (inb) {
      #pragma unroll 4
      for (int g = 0; g < NG; ++g) {
        float4 gb = sbox[g];
        float iw = fminf(gb.z, p.z) - fmaxf(gb.x, p.x);
        float ih = fminf(gb.w, p.w) - fmaxf(gb.y, p.y);
        iw = fmaxf(iw, 0.f);
        ih = fmaxf(ih, 0.f);
        float inter = iw * ih;
        float den   = sarea[g] + a2 - inter + 1e-9f;
        float iou   = inter / den;
        ins3(iou, t0, t1, t2);
      }
    }
    wave_top3(t0, t1, t2);
    if ((tid & 63) == 0) { bt[1] = t1; bt[2] = t2; }
  }
  // ---- unconditional per-wave max (slot 0; t0 == wmax on the slow path) ----
  if ((tid & 63) == 0) bt[0] = wmax;

  __syncthreads();   // fences the zero-fill stores vs the scatter below

  // ---- one-hot scatter (own row; zero-fill is fenced by the barrier) ----
  if (inb && maskv) outS[((long)b * NA + a) * NC + blab] = 1.f;
}

// ---------------------------------------------------------------------------
// P3: fallback fixup. Fast path: reduce max over the per-wave maxima in
// blockTop[...][0] (528 stride-3 floats/batch, L2-hot) and exit uniformly
// if the batch has any fg anchor — before any ballot / GT staging / triple
// work. Slow path (never taken on this data, kept correct): ballot over
// gmask, full top-3 reduce of blockTop triples for min_iou, per-anchor
// rewrite + one-hot scatter. need_fb implies P1 wrote the batch entirely as
// background (scores all zero), so only rewrites are needed; target_gt_idx
// is fallback-independent -> not rewritten.
// ---------------------------------------------------------------------------
__global__ __launch_bounds__(TPB) void p3_kernel(
    const float4* __restrict__ pd, const float4* __restrict__ gt,
    const int* __restrict__ glab, const int* __restrict__ gmask,
    const float* __restrict__ blockTop,
    float* __restrict__ outL, float4* __restrict__ outB,
    float* __restrict__ outS, float* __restrict__ outF)
{
  #pragma clang fp contract(off)
  const int b   = blockIdx.y;
  const int tid = threadIdx.x;

  __shared__ float  swm[NW];
  __shared__ float  sM;
  __shared__ float  swt[NW][3];
  __shared__ float  sres;
  __shared__ int    sfb;
  __shared__ float4 sbox[NG];
  __shared__ float  sarea[NG];
  __shared__ int    slab[NG];
  __shared__ int    svalid[NG];

  // ---- fast decision: max over this batch's per-wave maxima (slot 0) ----
  float m = -INFINITY;
  for (int i = tid; i < NBLK * NW; i += TPB)
    m = fmaxf(m, blockTop[((long)b * NBLK * NW + i) * 3]);
  #pragma unroll
  for (int off = 32; off > 0; off >>= 1)
    m = fmaxf(m, __shfl_xor(m, off, 64));
  const int lane = tid & 63, wid = tid >> 6;
  if (lane == 0) swm[wid] = m;
  __syncthreads();
  if (tid == 0) {
    float r = swm[0];
    #pragma unroll
    for (int w = 1; w < NW; ++w) r = fmaxf(r, swm[w]);
    sM = r;
  }
  __syncthreads();
  if (sM > 0.3f) return;       // common case: batch has fg -> uniform exit

  // ================= slow path (cold, correctness only) =================
  int gv = (tid < NG) ? gmask[b * NG + tid] : 0;
  unsigned long long bal = __ballot(gv != 0);  // valid in wave 0

  // reduce batch's per-wave top3 triples (all freshly written: global
  // fallback implies every p1 wave took the rare path)
  float t0 = -INFINITY, t1 = -INFINITY, t2 = -INFINITY;
  for (int i = tid; i < NBLK * NW; i += TPB) {
    const float* bt = blockTop + ((long)b * NBLK * NW + i) * 3;
    ins3(bt[0], t0, t1, t2);
    ins3(bt[1], t0, t1, t2);
    ins3(bt[2], t0, t1, t2);
  }
  wave_top3(t0, t1, t2);
  if (lane == 0) { swt[wid][0] = t0; swt[wid][1] = t1; swt[wid][2] = t2; }
  __syncthreads();
  if (tid == 0) {
    float r0 = swt[0][0], r1 = swt[0][1], r2 = swt[0][2];
    #pragma unroll
    for (int w = 1; w < NW; ++w) {
      ins3(swt[w][0], r0, r1, r2);
      ins3(swt[w][1], r0, r1, r2);
      ins3(swt[w][2], r0, r1, r2);
    }
    sfb  = (!(r0 > 0.3f) && bal != 0ULL) ? 1 : 0;
    sres = r2;
  }
  // stage gt into LDS (overlaps the decision barrier)
  if (tid < NG) {
    float4 g = gt[b * NG + tid];
    if (!gv) g = make_float4(0.f, 0.f, 0.f, 0.f);
    sbox[tid]   = g;
    sarea[tid]  = (g.z - g.x) * (g.w - g.y);
    slab[tid]   = glab[b * NG + tid];
    svalid[tid] = gv;
  }
  __syncthreads();
  if (sfb == 0) return;        // uniform exit (no barriers after this)
  const float minio = sres;

  const int a = blockIdx.x * TPB + tid;
  if (a >= NA) return;

  float4 p  = pd[(long)b * NA + a];
  float  a2 = (p.z - p.x) * (p.w - p.y);
  float best = -1.f;
  int   bidx = 0;
  #pragma unroll 8
  for (int g = 0; g < NG; ++g) {
    float4 gb = sbox[g];
    float iw = fminf(gb.z, p.z) - fmaxf(gb.x, p.x);
    float ih = fminf(gb.w, p.w) - fmaxf(gb.y, p.y);
    iw = fmaxf(iw, 0.f);
    ih = fmaxf(ih, 0.f);
    float inter = iw * ih;
    float den   = sarea[g] + a2 - inter + 1e-9f;
    float iou   = inter / den;
    bidx = (iou > best) ? g : bidx;
    best = fmaxf(best, iou);
  }
  // fallback fg: max over valid of overlaps >= min_iou. With zero-boxes and
  // has_valid guaranteed here, max over all g == max over valid g.
  bool fg    = best >= minio;
  bool maskv = fg && (svalid[bidx] != 0);
  int  blab  = slab[bidx];
  long ga = (long)b * NA + a;
  outL[ga] = maskv ? (float)blab : 80.f;
  float mm = maskv ? 1.f : 0.f;
  float4 gb = sbox[bidx];
  outB[ga] = make_float4(gb.x * mm, gb.y * mm, gb.z * mm, gb.w * mm);
  outF[ga] = fg ? 1.f : 0.f;
  if (maskv) outS[ga * NC + blab] = 1.f;  // scores were all-zero for this batch
}

// ---------------------------------------------------------------------------
// launch
// ---------------------------------------------------------------------------
extern "C" void kernel_launch(void* const* d_in, const int* in_sizes, int n_in,
                              void* d_out, int out_size, void* d_ws, size_t ws_size,
                              hipStream_t stream) {
  // inputs (setup_inputs order): 0 pd_scores (unused), 1 pd_bboxes,
  // 2 anc_points (unused), 3 gt_labels, 4 gt_bboxes, 5 mask_gt
  const float4* pd    = (const float4*)d_in[1];
  const int*    glab  = (const int*)d_in[3];
  const float4* gt    = (const float4*)d_in[4];
  const int*    gmask = (const int*)d_in[5];

  float* outf = (float*)d_out;
  // outputs concatenated flat in return order (all as float32):
  // target_labels [16,33600], target_bboxes [16,33600,4],
  // target_scores [16,33600,80], fg_mask [16,33600], target_gt_idx [16,33600]
  float*  outL = outf;
  float4* outB = (float4*)(outf + (long)BS * NA);
  float*  outS = outf + (long)BS * NA * 5;
  float*  outF = outf + (long)BS * NA * 5 + (long)BS * NA * NC;
  float*  outI = outF + (long)BS * NA;

  // workspace: per-wave {max, top3-tail} triples — exactly the proven
  // BS*NBLK*NW*3 floats (~101 KB), no growth vs the verified baseline.
  float* blockTop = (float*)d_ws;

  dim3 grid(NBLK, BS);
  p1_kernel<<<grid, TPB, 0, stream>>>(pd, gt, glab, gmask,
                                      outL, outB, outS, outF, outI, blockTop);
  p3_kernel<<<grid, TPB, 0, stream>>>(pd, gt, glab, gmask, blockTop,
                                      outL, outB, outS, outF);
}

// Round 4
// 284.642 us; speedup vs baseline: 1.1157x; 1.0375x over previous
//
#include <hip/hip_runtime.h>
#include <math.h>

// Problem constants (from reference setup_inputs)
#define NC 80            // NUM_CLASSES
constexpr int BS  = 16;      // batch
constexpr int NA  = 33600;   // anchors
constexpr int NG  = 64;      // gt boxes
constexpr int TPB = 256;
constexpr int NBLK = (NA + TPB - 1) / TPB;  // 132 blocks per batch
constexpr int NW   = TPB / 64;              // 4 waves per block
constexpr int NC4  = NC / 4;                // 20 float4 per score row

typedef float f32x4 __attribute__((ext_vector_type(4)));

// branchless insert of v into descending top-3 (t0 >= t1 >= t2): 6 VALU ops
__device__ __forceinline__ void ins3(float v, float& t0, float& t1, float& t2) {
  t2 = fmaxf(t2, fminf(v, t1));   // uses old t1
  t1 = fmaxf(t1, fminf(v, t0));   // uses old t0
  t0 = fmaxf(t0, v);
}

// 64-lane butterfly top3 merge
__device__ __forceinline__ void wave_top3(float& t0, float& t1, float& t2) {
  #pragma unroll
  for (int off = 32; off > 0; off >>= 1) {
    float u0 = __shfl_xor(t0, off, 64);
    float u1 = __shfl_xor(t1, off, 64);
    float u2 = __shfl_xor(t2, off, 64);
    ins3(u0, t0, t1, t2);
    ins3(u1, t0, t1, t2);
    ins3(u2, t0, t1, t2);
  }
}

// ---------------------------------------------------------------------------
// P1: fused main pass, SINGLE-PASS one-hot. R2 proved split-fill is −19 µs;
// R3 proved p1 is not VALU-bound (deferred top-3 bought only 2.6 µs). This
// round removes the remaining two-pass outS structure: instead of
// {172 MB zero-fill -> drain barrier -> sparse scatter}, the IoU phase
// parks each row's one-hot class in LDS (scls, −1 = background) and a
// single coalesced pass emits the block's whole 80 KB score tile with the
// one-hot value computed inline — outS written exactly once, nontemporal
// (never re-read), and the barrier now only publishes 1 KB of LDS instead
// of ordering two 80 KB store sets. IoU loop: exact IEEE divide, every
// comparison bit-identical to numpy. Deferred top-3 behind the wave-uniform
// wmax<=0.3 gate (global fallback implies ALL waves take it -> triples the
// slow consumer reads are always fresh). blockTop slot 0 carries wmax
// (== t0 on the slow path); footprint exactly BS*NBLK*NW*3 floats.
// Invalid GT boxes are zeroed in LDS so their IoU is exactly 0.0.
// ---------------------------------------------------------------------------
__global__ __launch_bounds__(TPB) void p1_kernel(
    const float4* __restrict__ pd, const float4* __restrict__ gt,
    const int* __restrict__ glab, const int* __restrict__ gmask,
    float* __restrict__ outL, float4* __restrict__ outB,
    float* __restrict__ outS, float* __restrict__ outF,
    float* __restrict__ outI, float* __restrict__ blockTop)
{
  #pragma clang fp contract(off)
  const int b   = blockIdx.y;
  const int tid = threadIdx.x;

  __shared__ float4 sbox[NG];
  __shared__ float  sarea[NG];
  __shared__ int    slab[NG];
  __shared__ int    svalid[NG];
  __shared__ int    scls[TPB];   // per-row one-hot class, -1 = background

  const int a0  = blockIdx.x * TPB;
  const int a   = a0 + tid;
  const bool inb = a < NA;

  // ---- own pd box (issued before the barrier) ----
  float4 p = make_float4(0.f, 0.f, 0.f, 0.f);
  if (inb) p = pd[(long)b * NA + a];

  // ---- stage gt into LDS ----
  if (tid < NG) {
    int v = gmask[b * NG + tid];
    float4 g = gt[b * NG + tid];
    if (!v) g = make_float4(0.f, 0.f, 0.f, 0.f);  // zero-box => iou == 0
    sbox[tid]   = g;
    sarea[tid]  = (g.z - g.x) * (g.w - g.y);
    slab[tid]   = glab[b * NG + tid];
    svalid[tid] = v;
  }
  __syncthreads();

  float best = -1.f;
  int   bidx = 0;
  float a2 = 0.f;
  bool  maskv = false;
  int   blab  = 0;

  if (inb) {
    a2 = (p.z - p.x) * (p.w - p.y);
    #pragma unroll 8
    for (int g = 0; g < NG; ++g) {
      float4 gb = sbox[g];
      float iw = fminf(gb.z, p.z) - fmaxf(gb.x, p.x);
      float ih = fminf(gb.w, p.w) - fmaxf(gb.y, p.y);
      iw = fmaxf(iw, 0.f);
      ih = fmaxf(ih, 0.f);
      float inter = iw * ih;
      float den   = sarea[g] + a2 - inter + 1e-9f;
      float iou   = inter / den;                 // exact IEEE, matches np
      bidx = (iou > best) ? g : bidx;            // first-index tie-break
      best = fmaxf(best, iou);
    }
    bool fg = best > 0.3f;
    maskv = fg && (svalid[bidx] != 0);
    blab  = slab[bidx];
    long ga = (long)b * NA + a;
    outL[ga] = maskv ? (float)blab : 80.f;       // BG_IDX = 80
    float m = maskv ? 1.f : 0.f;
    float4 gb = sbox[bidx];
    outB[ga] = make_float4(gb.x * m, gb.y * m, gb.z * m, gb.w * m);
    outF[ga] = fg ? 1.f : 0.f;
    outI[ga] = (float)bidx;
  }
  scls[tid] = maskv ? blab : -1;   // OOB rows get -1 but are never read

  // ---- per-wave max of best (cheap: 6 shfl + 6 fmax) ----
  float wmax = best;
  #pragma unroll
  for (int off = 32; off > 0; off >>= 1)
    wmax = fmaxf(wmax, __shfl_xor(wmax, off, 64));

  float* bt = blockTop + (((long)b * NBLK + blockIdx.x) * NW + (tid >> 6)) * 3;

  // ---- rare path: this wave cannot prove fg. Recompute ious with full
  // top-3 tracking and publish the triple's tail. Global need_fb implies
  // ALL waves land here, so the triples the slow consumer reads are always
  // freshly written. (OOB tail waves publish -inf tails and wmax=-1 — both
  // below any real iou >= 0, so the batch top-3, always >= 0 with 33600
  // real anchors, is unaffected.) ----
  if (wmax <= 0.3f) {                            // wave-uniform branch
    float t0 = -INFINITY, t1 = -INFINITY, t2 = -INFINITY;
    if (inb) {
      #pragma unroll 4
      for (int g = 0; g < NG; ++g) {
        float4 gb = sbox[g];
        float iw = fminf(gb.z, p.z) - fmaxf(gb.x, p.x);
        float ih = fminf(gb.w, p.w) - fmaxf(gb.y, p.y);
        iw = fmaxf(iw, 0.f);
        ih = fmaxf(ih, 0.f);
        float inter = iw * ih;
        float den   = sarea[g] + a2 - inter + 1e-9f;
        float iou   = inter / den;
        ins3(iou, t0, t1, t2);
      }
    }
    wave_top3(t0, t1, t2);
    if ((tid & 63) == 0) { bt[1] = t1; bt[2] = t2; }
  }
  // ---- unconditional per-wave max (slot 0; t0 == wmax on the slow path) ----
  if ((tid & 63) == 0) bt[0] = wmax;

  __syncthreads();   // publish scls (1 KB LDS) to the whole block

  // ---- single-pass coalesced one-hot emit: the block's whole score tile,
  // written exactly once, nontemporal (never re-read on the hot path) ----
  const int nA   = min(TPB, NA - a0);
  const int cnt4 = nA * NC4;
  f32x4* s4 = reinterpret_cast<f32x4*>(outS + ((long)b * NA + a0) * NC);
  for (int i = tid; i < cnt4; i += TPB) {
    int row = i / NC4;               // magic-mul div by 20
    int c0  = (i - row * NC4) * 4;   // starting class of this float4
    int cls = scls[row];
    f32x4 v;
    v.x = (cls == c0    ) ? 1.f : 0.f;
    v.y = (cls == c0 + 1) ? 1.f : 0.f;
    v.z = (cls == c0 + 2) ? 1.f : 0.f;
    v.w = (cls == c0 + 3) ? 1.f : 0.f;
    __builtin_nontemporal_store(v, s4 + i);
  }
}

// ---------------------------------------------------------------------------
// P3: fallback fixup. Fast path: reduce max over the per-wave maxima in
// blockTop[...][0] (528 stride-3 floats/batch, L2-hot) and exit uniformly
// if the batch has any fg anchor — before any ballot / GT staging / triple
// work. Slow path (never taken on this data, kept correct): ballot over
// gmask, full top-3 reduce of blockTop triples for min_iou, per-anchor
// rewrite + one-hot scatter. need_fb implies P1 wrote the batch entirely as
// background (scls == -1 everywhere -> score rows all zero), so only
// rewrites are needed; target_gt_idx is fallback-independent -> untouched.
// ---------------------------------------------------------------------------
__global__ __launch_bounds__(TPB) void p3_kernel(
    const float4* __restrict__ pd, const float4* __restrict__ gt,
    const int* __restrict__ glab, const int* __restrict__ gmask,
    const float* __restrict__ blockTop,
    float* __restrict__ outL, float4* __restrict__ outB,
    float* __restrict__ outS, float* __restrict__ outF)
{
  #pragma clang fp contract(off)
  const int b   = blockIdx.y;
  const int tid = threadIdx.x;

  __shared__ float  swm[NW];
  __shared__ float  sM;
  __shared__ float  swt[NW][3];
  __shared__ float  sres;
  __shared__ int    sfb;
  __shared__ float4 sbox[NG];
  __shared__ float  sarea[NG];
  __shared__ int    slab[NG];
  __shared__ int    svalid[NG];

  // ---- fast decision: max over this batch's per-wave maxima (slot 0) ----
  float m = -INFINITY;
  for (int i = tid; i < NBLK * NW; i += TPB)
    m = fmaxf(m, blockTop[((long)b * NBLK * NW + i) * 3]);
  #pragma unroll
  for (int off = 32; off > 0; off >>= 1)
    m = fmaxf(m, __shfl_xor(m, off, 64));
  const int lane = tid & 63, wid = tid >> 6;
  if (lane == 0) swm[wid] = m;
  __syncthreads();
  if (tid == 0) {
    float r = swm[0];
    #pragma unroll
    for (int w = 1; w < NW; ++w) r = fmaxf(r, swm[w]);
    sM = r;
  }
  __syncthreads();
  if (sM > 0.3f) return;       // common case: batch has fg -> uniform exit

  // ================= slow path (cold, correctness only) =================
  int gv = (tid < NG) ? gmask[b * NG + tid] : 0;
  unsigned long long bal = __ballot(gv != 0);  // valid in wave 0

  // reduce batch's per-wave top3 triples (all freshly written: global
  // fallback implies every p1 wave took the rare path)
  float t0 = -INFINITY, t1 = -INFINITY, t2 = -INFINITY;
  for (int i = tid; i < NBLK * NW; i += TPB) {
    const float* bt = blockTop + ((long)b * NBLK * NW + i) * 3;
    ins3(bt[0], t0, t1, t2);
    ins3(bt[1], t0, t1, t2);
    ins3(bt[2], t0, t1, t2);
  }
  wave_top3(t0, t1, t2);
  if (lane == 0) { swt[wid][0] = t0; swt[wid][1] = t1; swt[wid][2] = t2; }
  __syncthreads();
  if (tid == 0) {
    float r0 = swt[0][0], r1 = swt[0][1], r2 = swt[0][2];
    #pragma unroll
    for (int w = 1; w < NW; ++w) {
      ins3(swt[w][0], r0, r1, r2);
      ins3(swt[w][1], r0, r1, r2);
      ins3(swt[w][2], r0, r1, r2);
    }
    sfb  = (!(r0 > 0.3f) && bal != 0ULL) ? 1 : 0;
    sres = r2;
  }
  // stage gt into LDS (overlaps the decision barrier)
  if (tid < NG) {
    float4 g = gt[b * NG + tid];
    if (!gv) g = make_float4(0.f, 0.f, 0.f, 0.f);
    sbox[tid]   = g;
    sarea[tid]  = (g.z - g.x) * (g.w - g.y);
    slab[tid]   = glab[b * NG + tid];
    svalid[tid] = gv;
  }
  __syncthreads();
  if (sfb == 0) return;        // uniform exit (no barriers after this)
  const float minio = sres;

  const int a = blockIdx.x * TPB + tid;
  if (a >= NA) return;

  float4 p  = pd[(long)b * NA + a];
  float  a2 = (p.z - p.x) * (p.w - p.y);
  float best = -1.f;
  int   bidx = 0;
  #pragma unroll 8
  for (int g = 0; g < NG; ++g) {
    float4 gb = sbox[g];
    float iw = fminf(gb.z, p.z) - fmaxf(gb.x, p.x);
    float ih = fminf(gb.w, p.w) - fmaxf(gb.y, p.y);
    iw = fmaxf(iw, 0.f);
    ih = fmaxf(ih, 0.f);
    float inter = iw * ih;
    float den   = sarea[g] + a2 - inter + 1e-9f;
    float iou   = inter / den;
    bidx = (iou > best) ? g : bidx;
    best = fmaxf(best, iou);
  }
  // fallback fg: max over valid of overlaps >= min_iou. With zero-boxes and
  // has_valid guaranteed here, max over all g == max over valid g.
  bool fg    = best >= minio;
  bool maskv = fg && (svalid[bidx] != 0);
  int  blab  = slab[bidx];
  long ga = (long)b * NA + a;
  outL[ga] = maskv ? (float)blab : 80.f;
  float mm = maskv ? 1.f : 0.f;
  float4 gb = sbox[bidx];
  outB[ga] = make_float4(gb.x * mm, gb.y * mm, gb.z * mm, gb.w * mm);
  outF[ga] = fg ? 1.f : 0.f;
  if (maskv) outS[ga * NC + blab] = 1.f;  // scores were all-zero for this batch
}

// ---------------------------------------------------------------------------
// launch
// ---------------------------------------------------------------------------
extern "C" void kernel_launch(void* const* d_in, const int* in_sizes, int n_in,
                              void* d_out, int out_size, void* d_ws, size_t ws_size,
                              hipStream_t stream) {
  // inputs (setup_inputs order): 0 pd_scores (unused), 1 pd_bboxes,
  // 2 anc_points (unused), 3 gt_labels, 4 gt_bboxes, 5 mask_gt
  const float4* pd    = (const float4*)d_in[1];
  const int*    glab  = (const int*)d_in[3];
  const float4* gt    = (const float4*)d_in[4];
  const int*    gmask = (const int*)d_in[5];

  float* outf = (float*)d_out;
  // outputs concatenated flat in return order (all as float32):
  // target_labels [16,33600], target_bboxes [16,33600,4],
  // target_scores [16,33600,80], fg_mask [16,33600], target_gt_idx [16,33600]
  float*  outL = outf;
  float4* outB = (float4*)(outf + (long)BS * NA);
  float*  outS = outf + (long)BS * NA * 5;
  float*  outF = outf + (long)BS * NA * 5 + (long)BS * NA * NC;
  float*  outI = outF + (long)BS * NA;

  // workspace: per-wave {max, top3-tail} triples — exactly the proven
  // BS*NBLK*NW*3 floats (~101 KB), no growth vs the verified baseline.
  float* blockTop = (float*)d_ws;

  dim3 grid(NBLK, BS);
  p1_kernel<<<grid, TPB, 0, stream>>>(pd, gt, glab, gmask,
                                      outL, outB, outS, outF, outI, blockTop);
  p3_kernel<<<grid, TPB, 0, stream>>>(pd, gt, glab, gmask, blockTop,
                                      outL, outB, outS, outF);
}

// Round 5
// 282.154 us; speedup vs baseline: 1.1255x; 1.0088x over previous
//
#include <hip/hip_runtime.h>
#include <math.h>

// Problem constants (from reference setup_inputs)
#define NC 80            // NUM_CLASSES
constexpr int BS  = 16;      // batch
constexpr int NA  = 33600;   // anchors
constexpr int NG  = 64;      // gt boxes
constexpr int TPB = 256;
constexpr int NBLK = (NA + TPB - 1) / TPB;  // 132 blocks per batch
constexpr int NW   = TPB / 64;              // 4 waves per block
constexpr int NC4  = NC / 4;                // 20 float4 per score row

typedef float f32x4 __attribute__((ext_vector_type(4)));

// branchless insert of v into descending top-3 (t0 >= t1 >= t2): 6 VALU ops
__device__ __forceinline__ void ins3(float v, float& t0, float& t1, float& t2) {
  t2 = fmaxf(t2, fminf(v, t1));   // uses old t1
  t1 = fmaxf(t1, fminf(v, t0));   // uses old t0
  t0 = fmaxf(t0, v);
}

// 64-lane butterfly top3 merge
__device__ __forceinline__ void wave_top3(float& t0, float& t1, float& t2) {
  #pragma unroll
  for (int off = 32; off > 0; off >>= 1) {
    float u0 = __shfl_xor(t0, off, 64);
    float u1 = __shfl_xor(t1, off, 64);
    float u2 = __shfl_xor(t2, off, 64);
    ins3(u0, t0, t1, t2);
    ins3(u1, t0, t1, t2);
    ins3(u2, t0, t1, t2);
  }
}

// ---------------------------------------------------------------------------
// P1: fused main pass, WAVE-LOCAL one-hot emit (no second barrier). R4
// proved the single-pass one-hot was the right structure (−10.7 µs); this
// round removes its last serialization: the block-wide __syncthreads that
// published scls forced a vmcnt(0) drain of every prior store before any
// wave could start the 80 KB emit. The emit's dependency is wave-local
// (wave w emits rows w*64..w*64+63, whose classes are held by its own
// lanes), so __shfl(own_cls, row) replaces LDS+barrier entirely — waves
// issue their emit stores immediately after their IoU loop and retire
// independently. IoU loop: exact IEEE divide, every comparison
// bit-identical to numpy. Deferred top-3 behind the wave-uniform
// wmax<=0.3 gate (global fallback implies ALL waves take it -> triples the
// slow consumer reads are always fresh). blockTop slot 0 carries wmax
// (== t0 on the slow path); footprint exactly BS*NBLK*NW*3 floats.
// Invalid GT boxes are zeroed in LDS so their IoU is exactly 0.0.
// ---------------------------------------------------------------------------
__global__ __launch_bounds__(TPB) void p1_kernel(
    const float4* __restrict__ pd, const float4* __restrict__ gt,
    const int* __restrict__ glab, const int* __restrict__ gmask,
    float* __restrict__ outL, float4* __restrict__ outB,
    float* __restrict__ outS, float* __restrict__ outF,
    float* __restrict__ outI, float* __restrict__ blockTop)
{
  #pragma clang fp contract(off)
  const int b   = blockIdx.y;
  const int tid = threadIdx.x;

  __shared__ float4 sbox[NG];
  __shared__ float  sarea[NG];
  __shared__ int    slab[NG];
  __shared__ int    svalid[NG];

  const int a0  = blockIdx.x * TPB;
  const int a   = a0 + tid;
  const bool inb = a < NA;

  // ---- own pd box (issued before the barrier) ----
  float4 p = make_float4(0.f, 0.f, 0.f, 0.f);
  if (inb) p = pd[(long)b * NA + a];

  // ---- stage gt into LDS ----
  if (tid < NG) {
    int v = gmask[b * NG + tid];
    float4 g = gt[b * NG + tid];
    if (!v) g = make_float4(0.f, 0.f, 0.f, 0.f);  // zero-box => iou == 0
    sbox[tid]   = g;
    sarea[tid]  = (g.z - g.x) * (g.w - g.y);
    slab[tid]   = glab[b * NG + tid];
    svalid[tid] = v;
  }
  __syncthreads();

  float best = -1.f;
  int   bidx = 0;
  float a2 = 0.f;
  bool  maskv = false;
  int   blab  = 0;

  if (inb) {
    a2 = (p.z - p.x) * (p.w - p.y);
    #pragma unroll 8
    for (int g = 0; g < NG; ++g) {
      float4 gb = sbox[g];
      float iw = fminf(gb.z, p.z) - fmaxf(gb.x, p.x);
      float ih = fminf(gb.w, p.w) - fmaxf(gb.y, p.y);
      iw = fmaxf(iw, 0.f);
      ih = fmaxf(ih, 0.f);
      float inter = iw * ih;
      float den   = sarea[g] + a2 - inter + 1e-9f;
      float iou   = inter / den;                 // exact IEEE, matches np
      bidx = (iou > best) ? g : bidx;            // first-index tie-break
      best = fmaxf(best, iou);
    }
    bool fg = best > 0.3f;
    maskv = fg && (svalid[bidx] != 0);
    blab  = slab[bidx];
    long ga = (long)b * NA + a;
    outL[ga] = maskv ? (float)blab : 80.f;       // BG_IDX = 80
    float m = maskv ? 1.f : 0.f;
    float4 gb = sbox[bidx];
    outB[ga] = make_float4(gb.x * m, gb.y * m, gb.z * m, gb.w * m);
    outF[ga] = fg ? 1.f : 0.f;
    outI[ga] = (float)bidx;
  }

  // ---- wave-local one-hot emit: wave w owns rows [w*64, w*64+64) of this
  // block's score tile; each row's class comes from the owning lane via
  // shfl. No barrier, no LDS — stores issue as soon as this wave's IoU
  // loop retires, and waves drain independently. Coalesced 64x16B lines,
  // nontemporal (outS is never re-read on the hot path). ----
  const int lane = tid & 63, wid = tid >> 6;
  const int nA    = min(TPB, NA - a0);
  const int wrow0 = wid * 64;                   // wave's first local row
  const int rows  = min(64, nA - wrow0);        // <=0 for fully-OOB waves
  const int own_cls = maskv ? blab : -1;        // -1 = background
  if (rows > 0) {
    f32x4* s4 = reinterpret_cast<f32x4*>(outS + ((long)b * NA + a0 + wrow0) * NC);
    const int cnt4 = rows * NC4;
    for (int i = lane; i < cnt4; i += 64) {
      int row = i / NC4;               // magic-mul div by 20
      int c0  = (i - row * NC4) * 4;   // starting class of this float4
      int cls = __shfl(own_cls, row, 64);
      f32x4 v;
      v.x = (cls == c0    ) ? 1.f : 0.f;
      v.y = (cls == c0 + 1) ? 1.f : 0.f;
      v.z = (cls == c0 + 2) ? 1.f : 0.f;
      v.w = (cls == c0 + 3) ? 1.f : 0.f;
      __builtin_nontemporal_store(v, s4 + i);
    }
  }

  // ---- per-wave max of best (cheap: 6 shfl + 6 fmax) ----
  float wmax = best;
  #pragma unroll
  for (int off = 32; off > 0; off >>= 1)
    wmax = fmaxf(wmax, __shfl_xor(wmax, off, 64));

  float* bt = blockTop + (((long)b * NBLK + blockIdx.x) * NW + wid) * 3;

  // ---- rare path: this wave cannot prove fg. Recompute ious with full
  // top-3 tracking and publish the triple's tail. Global need_fb implies
  // ALL waves land here, so the triples the slow consumer reads are always
  // freshly written. (OOB tail waves publish -inf tails and wmax=-1 — both
  // below any real iou >= 0, so the batch top-3, always >= 0 with 33600
  // real anchors, is unaffected.) ----
  if (wmax <= 0.3f) {                            // wave-uniform branch
    float t0 = -INFINITY, t1 = -INFINITY, t2 = -INFINITY;
    if (inb) {
      #pragma unroll 4
      for (int g = 0; g < NG; ++g) {
        float4 gb = sbox[g];
        float iw = fminf(gb.z, p.z) - fmaxf(gb.x, p.x);
        float ih = fminf(gb.w, p.w) - fmaxf(gb.y, p.y);
        iw = fmaxf(iw, 0.f);
        ih = fmaxf(ih, 0.f);
        float inter = iw * ih;
        float den   = sarea[g] + a2 - inter + 1e-9f;
        float iou   = inter / den;
        ins3(iou, t0, t1, t2);
      }
    }
    wave_top3(t0, t1, t2);
    if (lane == 0) { bt[1] = t1; bt[2] = t2; }
  }
  // ---- unconditional per-wave max (slot 0; t0 == wmax on the slow path) ----
  if (lane == 0) bt[0] = wmax;
}

// ---------------------------------------------------------------------------
// P3: fallback fixup, ONE BLOCK PER BATCH (grid = BS). The 2112-block
// version redundantly reduced the same 528 floats in every block just to
// decide "exit"; one block per batch makes the identical decision with
// ~1/130th the work. Cold path (never taken on this data, kept correct):
// ballot over gmask, full top-3 reduce of blockTop triples for min_iou,
// then a grid-stride loop over all NA anchors doing the rewrite + one-hot
// scatter from this single block. need_fb implies P1 wrote the batch
// entirely as background (scores all zero), so only rewrites are needed;
// target_gt_idx is fallback-independent -> untouched.
// ---------------------------------------------------------------------------
__global__ __launch_bounds__(TPB) void p3_kernel(
    const float4* __restrict__ pd, const float4* __restrict__ gt,
    const int* __restrict__ glab, const int* __restrict__ gmask,
    const float* __restrict__ blockTop,
    float* __restrict__ outL, float4* __restrict__ outB,
    float* __restrict__ outS, float* __restrict__ outF)
{
  #pragma clang fp contract(off)
  const int b   = blockIdx.x;
  const int tid = threadIdx.x;

  __shared__ float  swm[NW];
  __shared__ float  sM;
  __shared__ float  swt[NW][3];
  __shared__ float  sres;
  __shared__ int    sfb;
  __shared__ float4 sbox[NG];
  __shared__ float  sarea[NG];
  __shared__ int    slab[NG];
  __shared__ int    svalid[NG];

  // ---- fast decision: max over this batch's per-wave maxima (slot 0) ----
  float m = -INFINITY;
  for (int i = tid; i < NBLK * NW; i += TPB)
    m = fmaxf(m, blockTop[((long)b * NBLK * NW + i) * 3]);
  #pragma unroll
  for (int off = 32; off > 0; off >>= 1)
    m = fmaxf(m, __shfl_xor(m, off, 64));
  const int lane = tid & 63, wid = tid >> 6;
  if (lane == 0) swm[wid] = m;
  __syncthreads();
  if (tid == 0) {
    float r = swm[0];
    #pragma unroll
    for (int w = 1; w < NW; ++w) r = fmaxf(r, swm[w]);
    sM = r;
  }
  __syncthreads();
  if (sM > 0.3f) return;       // common case: batch has fg -> uniform exit

  // ================= slow path (cold, correctness only) =================
  int gv = (tid < NG) ? gmask[b * NG + tid] : 0;
  unsigned long long bal = __ballot(gv != 0);  // valid in wave 0

  // reduce batch's per-wave top3 triples (all freshly written: global
  // fallback implies every p1 wave took the rare path)
  float t0 = -INFINITY, t1 = -INFINITY, t2 = -INFINITY;
  for (int i = tid; i < NBLK * NW; i += TPB) {
    const float* bt = blockTop + ((long)b * NBLK * NW + i) * 3;
    ins3(bt[0], t0, t1, t2);
    ins3(bt[1], t0, t1, t2);
    ins3(bt[2], t0, t1, t2);
  }
  wave_top3(t0, t1, t2);
  if (lane == 0) { swt[wid][0] = t0; swt[wid][1] = t1; swt[wid][2] = t2; }
  __syncthreads();
  if (tid == 0) {
    float r0 = swt[0][0], r1 = swt[0][1], r2 = swt[0][2];
    #pragma unroll
    for (int w = 1; w < NW; ++w) {
      ins3(swt[w][0], r0, r1, r2);
      ins3(swt[w][1], r0, r1, r2);
      ins3(swt[w][2], r0, r1, r2);
    }
    sfb  = (!(r0 > 0.3f) && bal != 0ULL) ? 1 : 0;
    sres = r2;
  }
  // stage gt into LDS (overlaps the decision barrier)
  if (tid < NG) {
    float4 g = gt[b * NG + tid];
    if (!gv) g = make_float4(0.f, 0.f, 0.f, 0.f);
    sbox[tid]   = g;
    sarea[tid]  = (g.z - g.x) * (g.w - g.y);
    slab[tid]   = glab[b * NG + tid];
    svalid[tid] = gv;
  }
  __syncthreads();
  if (sfb == 0) return;        // uniform exit (no barriers after this)
  const float minio = sres;

  // grid-stride rewrite of the whole batch from this single block (cold)
  for (int a = tid; a < NA; a += TPB) {
    float4 p  = pd[(long)b * NA + a];
    float  a2 = (p.z - p.x) * (p.w - p.y);
    float best = -1.f;
    int   bidx = 0;
    #pragma unroll 8
    for (int g = 0; g < NG; ++g) {
      float4 gb = sbox[g];
      float iw = fminf(gb.z, p.z) - fmaxf(gb.x, p.x);
      float ih = fminf(gb.w, p.w) - fmaxf(gb.y, p.y);
      iw = fmaxf(iw, 0.f);
      ih = fmaxf(ih, 0.f);
      float inter = iw * ih;
      float den   = sarea[g] + a2 - inter + 1e-9f;
      float iou   = inter / den;
      bidx = (iou > best) ? g : bidx;
      best = fmaxf(best, iou);
    }
    // fallback fg: max over valid of overlaps >= min_iou. With zero-boxes
    // and has_valid guaranteed here, max over all g == max over valid g.
    bool fg    = best >= minio;
    bool maskv = fg && (svalid[bidx] != 0);
    int  blab  = slab[bidx];
    long ga = (long)b * NA + a;
    outL[ga] = maskv ? (float)blab : 80.f;
    float mm = maskv ? 1.f : 0.f;
    float4 gb = sbox[bidx];
    outB[ga] = make_float4(gb.x * mm, gb.y * mm, gb.z * mm, gb.w * mm);
    outF[ga] = fg ? 1.f : 0.f;
    if (maskv) outS[ga * NC + blab] = 1.f;  // scores were all-zero here
  }
}

// ---------------------------------------------------------------------------
// launch
// ---------------------------------------------------------------------------
extern "C" void kernel_launch(void* const* d_in, const int* in_sizes, int n_in,
                              void* d_out, int out_size, void* d_ws, size_t ws_size,
                              hipStream_t stream) {
  // inputs (setup_inputs order): 0 pd_scores (unused), 1 pd_bboxes,
  // 2 anc_points (unused), 3 gt_labels, 4 gt_bboxes, 5 mask_gt
  const float4* pd    = (const float4*)d_in[1];
  const int*    glab  = (const int*)d_in[3];
  const float4* gt    = (const float4*)d_in[4];
  const int*    gmask = (const int*)d_in[5];

  float* outf = (float*)d_out;
  // outputs concatenated flat in return order (all as float32):
  // target_labels [16,33600], target_bboxes [16,33600,4],
  // target_scores [16,33600,80], fg_mask [16,33600], target_gt_idx [16,33600]
  float*  outL = outf;
  float4* outB = (float4*)(outf + (long)BS * NA);
  float*  outS = outf + (long)BS * NA * 5;
  float*  outF = outf + (long)BS * NA * 5 + (long)BS * NA * NC;
  float*  outI = outF + (long)BS * NA;

  // workspace: per-wave {max, top3-tail} triples — exactly the proven
  // BS*NBLK*NW*3 floats (~101 KB), no growth vs the verified baseline.
  float* blockTop = (float*)d_ws;

  dim3 grid(NBLK, BS);
  p1_kernel<<<grid, TPB, 0, stream>>>(pd, gt, glab, gmask,
                                      outL, outB, outS, outF, outI, blockTop);
  p3_kernel<<<BS, TPB, 0, stream>>>(pd, gt, glab, gmask, blockTop,
                                    outL, outB, outS, outF);
}